// Round 3
// baseline (585.790 us; speedup 1.0000x reference)
//
#include <hip/hip_runtime.h>
#include <stdint.h>

#define N_NODES 131072
#define HDIM 128

typedef __bf16 bf16x8 __attribute__((ext_vector_type(8)));
typedef float f32x4 __attribute__((ext_vector_type(4)));
typedef unsigned short us8 __attribute__((ext_vector_type(8)));
typedef unsigned short ushort_t;

__device__ __forceinline__ float bf2f(ushort_t u) {
    union { float f; uint32_t i; } v; v.i = ((uint32_t)u) << 16; return v.f;
}
__device__ __forceinline__ ushort_t f2bf(float f) {
    union { float f; uint32_t i; } v; v.f = f;
    uint32_t i = v.i;
    return (ushort_t)((i + 0x7FFFu + ((i >> 16) & 1u)) >> 16);  // RNE
}

// ---------------------------------------------------------------------------
// One-time prep: fp32->bf16 weight conversion (+ transpose for GCN weights).
// Total 335872 elements -> 1312 blocks x 256.
// ---------------------------------------------------------------------------
__global__ __launch_bounds__(256) void prep_weights(
    const float* __restrict__ w_f1, const float* __restrict__ w_b1,
    const float* __restrict__ w_f2, const float* __restrict__ w_b2,
    const float* __restrict__ w_g1, const float* __restrict__ w_g2,
    ushort_t* __restrict__ PWF1, ushort_t* __restrict__ PWB1,
    ushort_t* __restrict__ PWF2, ushort_t* __restrict__ PWB2,
    ushort_t* __restrict__ WT1,  ushort_t* __restrict__ WT2)
{
    int idx = blockIdx.x * 256 + threadIdx.x;
    if (idx < 49152) {
        PWF1[idx] = f2bf(w_f1[idx]);
    } else if (idx < 98304) {
        int j = idx - 49152;  PWB1[j] = f2bf(w_b1[j]);
    } else if (idx < 196608) {
        int j = idx - 98304;  PWF2[j] = f2bf(w_f2[j]);
    } else if (idx < 294912) {
        int j = idx - 196608; PWB2[j] = f2bf(w_b2[j]);
    } else if (idx < 327680) {
        int j = idx - 294912; int k = j >> 7, o = j & 127;   // w_g1 [256,128]
        WT1[o * 256 + k] = f2bf(w_g1[j]);                    // WT1 [128,256]
    } else if (idx < 335872) {
        int j = idx - 327680; int k = j >> 6, o = j & 63;    // w_g2 [128,64]
        WT2[o * 128 + k] = f2bf(w_g2[j]);                    // WT2 [64,128]
    }
}

// ---------------------------------------------------------------------------
// Fused GRU GEMM: gi = A @ W^T, then PyTorch GRU cell with h_prev=0:
//   r = sig(ir+bi_r+bh_r); z = sig(iz+bi_z+bh_z); n = tanh(inn+bi_n+r*bh_n)
//   h = (1-z)*n
// Block tile: 128 rows x 32 j-cols, all 3 gate strips. AF32: A is fp32,
// converted to bf16 during LDS staging.
// ---------------------------------------------------------------------------
template<int K, bool AF32>
__global__ __launch_bounds__(256) void gru_gemm(
    const void* __restrict__ Ap,        // [N_NODES, K] fp32 (AF32) or bf16
    const ushort_t* __restrict__ W,     // [384, K] bf16 (prepped, row-major = B^T)
    const float* __restrict__ b_ih,     // [384] fp32
    const float* __restrict__ b_hh,     // [384] fp32
    ushort_t* __restrict__ Hout,        // [N_NODES, 256] bf16
    int coloff)
{
    __shared__ ushort_t As[128 * 136];  // stride 136: rows stay 16B-aligned
    __shared__ ushort_t Bs[96 * 136];
    const int tid = threadIdx.x;
    const int m0 = blockIdx.x * 128;
    const int j0 = blockIdx.y * 32;
    const int wv = tid >> 6;
    const int lane = tid & 63;
    const int lr = lane & 15;
    const int lq = lane >> 4;

    f32x4 acc[3][2][2];
    #pragma unroll
    for (int g = 0; g < 3; ++g)
        #pragma unroll
        for (int rt = 0; rt < 2; ++rt)
            #pragma unroll
            for (int ct = 0; ct < 2; ++ct)
                #pragma unroll
                for (int e = 0; e < 4; ++e) acc[g][rt][ct][e] = 0.0f;

    for (int t = 0; t < K / 128; ++t) {
        const int k0 = t * 128;
        // stage A tile: 128x128 bf16 (convert from fp32 if AF32)
        #pragma unroll
        for (int c = tid; c < 2048; c += 256) {
            int row = c >> 4, col = (c & 15) << 3;
            if (AF32) {
                const float* A = (const float*)Ap;
                const float* src = &A[(size_t)(m0 + row) * K + k0 + col];
                float4 f0 = *(const float4*)src;
                float4 f1 = *(const float4*)(src + 4);
                us8 tv;
                tv[0] = f2bf(f0.x); tv[1] = f2bf(f0.y);
                tv[2] = f2bf(f0.z); tv[3] = f2bf(f0.w);
                tv[4] = f2bf(f1.x); tv[5] = f2bf(f1.y);
                tv[6] = f2bf(f1.z); tv[7] = f2bf(f1.w);
                *(us8*)&As[row * 136 + col] = tv;
            } else {
                const ushort_t* A = (const ushort_t*)Ap;
                *(uint4*)&As[row * 136 + col] =
                    *(const uint4*)&A[(size_t)(m0 + row) * K + k0 + col];
            }
        }
        // stage B tile: 3 gate strips x 32 rows of W (bf16)
        #pragma unroll
        for (int c = tid; c < 1536; c += 256) {
            int row = c >> 4, col = (c & 15) << 3;
            int g = row >> 5, jj = row & 31;
            *(uint4*)&Bs[row * 136 + col] =
                *(const uint4*)&W[(size_t)(g * HDIM + j0 + jj) * K + k0 + col];
        }
        __syncthreads();
        #pragma unroll
        for (int kk = 0; kk < 128; kk += 32) {
            const int ko = kk + lq * 8;
            bf16x8 a0 = *(const bf16x8*)&As[(wv * 32 + lr) * 136 + ko];
            bf16x8 a1 = *(const bf16x8*)&As[(wv * 32 + 16 + lr) * 136 + ko];
            #pragma unroll
            for (int g = 0; g < 3; ++g) {
                #pragma unroll
                for (int ct = 0; ct < 2; ++ct) {
                    bf16x8 b = *(const bf16x8*)&Bs[(g * 32 + ct * 16 + lr) * 136 + ko];
                    acc[g][0][ct] = __builtin_amdgcn_mfma_f32_16x16x32_bf16(a0, b, acc[g][0][ct], 0, 0, 0);
                    acc[g][1][ct] = __builtin_amdgcn_mfma_f32_16x16x32_bf16(a1, b, acc[g][1][ct], 0, 0, 0);
                }
            }
        }
        __syncthreads();
    }

    // epilogue: C/D layout col=lane&15, row=(lane>>4)*4+reg  [verified m89/m91]
    #pragma unroll
    for (int ct = 0; ct < 2; ++ct) {
        const int j = j0 + ct * 16 + lr;          // 0..127
        const float br  = b_ih[j] + b_hh[j];
        const float bz  = b_ih[HDIM + j] + b_hh[HDIM + j];
        const float bn  = b_ih[2 * HDIM + j];
        const float bhn = b_hh[2 * HDIM + j];
        #pragma unroll
        for (int rt = 0; rt < 2; ++rt) {
            #pragma unroll
            for (int r = 0; r < 4; ++r) {
                const int row = m0 + wv * 32 + rt * 16 + lq * 4 + r;
                float ir = acc[0][rt][ct][r] + br;
                float iz = acc[1][rt][ct][r] + bz;
                float rg = 1.0f / (1.0f + expf(-ir));
                float zg = 1.0f / (1.0f + expf(-iz));
                float ng = tanhf(acc[2][rt][ct][r] + bn + rg * bhn);
                Hout[(size_t)row * 256 + coloff + j] = f2bf((1.0f - zg) * ng);
            }
        }
    }
}

// ---------------------------------------------------------------------------
// Plain GEMM: Out = A @ Wt^T, Wt [Nout, K] bf16 (pre-transposed). 128x64 tile.
// ---------------------------------------------------------------------------
template<int K>
__global__ __launch_bounds__(256) void gemm_bt(
    const ushort_t* __restrict__ A,   // [N_NODES, K] bf16
    const ushort_t* __restrict__ Wt,  // [Nout, K] bf16
    ushort_t* __restrict__ Out,       // [N_NODES, Nld] bf16
    int Nld)
{
    __shared__ ushort_t As[128 * 136];
    __shared__ ushort_t Bs[64 * 136];
    const int tid = threadIdx.x;
    const int m0 = blockIdx.x * 128;
    const int n0 = blockIdx.y * 64;
    const int wv = tid >> 6;
    const int lane = tid & 63;
    const int lr = lane & 15;
    const int lq = lane >> 4;

    f32x4 acc[2][4];
    #pragma unroll
    for (int rt = 0; rt < 2; ++rt)
        #pragma unroll
        for (int ct = 0; ct < 4; ++ct)
            #pragma unroll
            for (int e = 0; e < 4; ++e) acc[rt][ct][e] = 0.0f;

    for (int t = 0; t < K / 128; ++t) {
        const int k0 = t * 128;
        #pragma unroll
        for (int c = tid; c < 2048; c += 256) {
            int row = c >> 4, col = (c & 15) << 3;
            *(uint4*)&As[row * 136 + col] =
                *(const uint4*)&A[(size_t)(m0 + row) * K + k0 + col];
        }
        #pragma unroll
        for (int c = tid; c < 1024; c += 256) {
            int row = c >> 4, col = (c & 15) << 3;
            *(uint4*)&Bs[row * 136 + col] =
                *(const uint4*)&Wt[(size_t)(n0 + row) * K + k0 + col];
        }
        __syncthreads();
        #pragma unroll
        for (int kk = 0; kk < 128; kk += 32) {
            const int ko = kk + lq * 8;
            bf16x8 a0 = *(const bf16x8*)&As[(wv * 32 + lr) * 136 + ko];
            bf16x8 a1 = *(const bf16x8*)&As[(wv * 32 + 16 + lr) * 136 + ko];
            #pragma unroll
            for (int ct = 0; ct < 4; ++ct) {
                bf16x8 b = *(const bf16x8*)&Bs[(ct * 16 + lr) * 136 + ko];
                acc[0][ct] = __builtin_amdgcn_mfma_f32_16x16x32_bf16(a0, b, acc[0][ct], 0, 0, 0);
                acc[1][ct] = __builtin_amdgcn_mfma_f32_16x16x32_bf16(a1, b, acc[1][ct], 0, 0, 0);
            }
        }
        __syncthreads();
    }

    #pragma unroll
    for (int ct = 0; ct < 4; ++ct) {
        const int col = n0 + ct * 16 + lr;
        #pragma unroll
        for (int rt = 0; rt < 2; ++rt) {
            #pragma unroll
            for (int r = 0; r < 4; ++r) {
                const int row = m0 + wv * 32 + rt * 16 + lq * 4 + r;
                Out[(size_t)row * Nld + col] = f2bf(acc[rt][ct][r]);
            }
        }
    }
}

// ---------------------------------------------------------------------------
// GCN chain aggregation: g[i] = di*(dm*x[i-1]+di*x[i]+dp*x[i+1]) + b
// deg = 2 at chain ends, 3 interior (self-loops included).
// ---------------------------------------------------------------------------
__global__ __launch_bounds__(256) void stencil128(
    const ushort_t* __restrict__ xw, const float* __restrict__ bias,
    ushort_t* __restrict__ g)
{
    const float S2 = 0.70710678118654752f, S3 = 0.57735026918962576f;
    int idx = blockIdx.x * 256 + threadIdx.x;   // N*128
    int i = idx >> 7, c = idx & 127;
    float di = (i == 0 || i == N_NODES - 1) ? S2 : S3;
    float s = di * bf2f(xw[idx]);
    if (i > 0) {
        float dm = (i - 1 == 0) ? S2 : S3;
        s += dm * bf2f(xw[idx - 128]);
    }
    if (i < N_NODES - 1) {
        float dp = (i + 1 == N_NODES - 1) ? S2 : S3;
        s += dp * bf2f(xw[idx + 128]);
    }
    g[idx] = f2bf(di * s + bias[c]);
}

// ---------------------------------------------------------------------------
// Final: GCN2 aggregation (C=64) + bias + FC [64->10] + bias, one thread/row.
// OUTPUT IS FP32 (reference returns float32; harness reads d_out as fp32).
// ---------------------------------------------------------------------------
__global__ __launch_bounds__(256) void final_fc(
    const ushort_t* __restrict__ xw2,   // [N,64] bf16
    const float* __restrict__ b_g2,     // [64] fp32
    const float* __restrict__ w_fc,     // [64,10] fp32
    const float* __restrict__ b_fc,     // [10] fp32
    float* __restrict__ out)            // [N,10] fp32
{
    __shared__ float wfc_s[640];
    __shared__ float bg2_s[64];
    __shared__ float bfc_s[10];
    const int tid = threadIdx.x;
    for (int t = tid; t < 640; t += 256) wfc_s[t] = w_fc[t];
    if (tid < 64) bg2_s[tid] = b_g2[tid];
    if (tid < 10) bfc_s[tid] = b_fc[tid];
    __syncthreads();

    const float S2 = 0.70710678118654752f, S3 = 0.57735026918962576f;
    const int i = blockIdx.x * 256 + tid;
    float di = (i == 0 || i == N_NODES - 1) ? S2 : S3;
    bool hm = i > 0, hp = i < N_NODES - 1;
    float dm = hm ? ((i - 1 == 0) ? S2 : S3) : 0.0f;
    float dp = hp ? ((i + 1 == N_NODES - 1) ? S2 : S3) : 0.0f;
    const ushort_t* r0 = xw2 + (size_t)i * 64;
    const ushort_t* rm = xw2 + (size_t)(hm ? i - 1 : i) * 64;
    const ushort_t* rp = xw2 + (size_t)(hp ? i + 1 : i) * 64;

    float o[10];
    #pragma unroll
    for (int k = 0; k < 10; ++k) o[k] = bfc_s[k];
    #pragma unroll 4
    for (int c = 0; c < 64; ++c) {
        float s = di * bf2f(r0[c]) + dm * bf2f(rm[c]) + dp * bf2f(rp[c]);
        float g2 = di * s + bg2_s[c];
        #pragma unroll
        for (int k = 0; k < 10; ++k) o[k] += g2 * wfc_s[c * 10 + k];
    }
    #pragma unroll
    for (int k = 0; k < 10; ++k) out[(size_t)i * 10 + k] = o[k];
}

extern "C" void kernel_launch(void* const* d_in, const int* in_sizes, int n_in,
                              void* d_out, int out_size, void* d_ws, size_t ws_size,
                              hipStream_t stream) {
    const float* x     = (const float*)d_in[0];
    const float* w_f1  = (const float*)d_in[1];
    const float* bi_f1 = (const float*)d_in[2];
    const float* bh_f1 = (const float*)d_in[3];
    const float* w_b1  = (const float*)d_in[4];
    const float* bi_b1 = (const float*)d_in[5];
    const float* bh_b1 = (const float*)d_in[6];
    const float* w_f2  = (const float*)d_in[7];
    const float* bi_f2 = (const float*)d_in[8];
    const float* bh_f2 = (const float*)d_in[9];
    const float* w_b2  = (const float*)d_in[10];
    const float* bi_b2 = (const float*)d_in[11];
    const float* bh_b2 = (const float*)d_in[12];
    const float* w_g1  = (const float*)d_in[13];
    const float* b_g1  = (const float*)d_in[14];
    const float* w_g2  = (const float*)d_in[15];
    const float* b_g2  = (const float*)d_in[16];
    const float* w_fc  = (const float*)d_in[17];
    const float* b_fc  = (const float*)d_in[18];

    char* ws = (char*)d_ws;
    // layout (peak ~134.9 MB):
    ushort_t* h1   = (ushort_t*)(ws);                    // [N,256] bf16, 67.1MB
    ushort_t* h2   = (ushort_t*)(ws + 67108864);         // [N,256] bf16, 67.1MB
    ushort_t* xw1  = (ushort_t*)(ws);                    // [N,128] reuse h1 (dead)
    ushort_t* g1   = (ushort_t*)(ws + 33554432);         // [N,128] upper half of h1
    ushort_t* xw2  = (ushort_t*)(ws + 67108864);         // [N,64]  reuse h2 (dead)
    ushort_t* PWF1 = (ushort_t*)(ws + 134217728);        // [384,128] bf16
    ushort_t* PWB1 = PWF1 + 49152;
    ushort_t* PWF2 = PWB1 + 49152;                       // [384,256] bf16
    ushort_t* PWB2 = PWF2 + 98304;
    ushort_t* WT1  = PWB2 + 98304;                       // [128,256] bf16
    ushort_t* WT2  = WT1 + 32768;                        // [64,128] bf16

    prep_weights<<<1312, 256, 0, stream>>>(w_f1, w_b1, w_f2, w_b2, w_g1, w_g2,
                                           PWF1, PWB1, PWF2, PWB2, WT1, WT2);

    dim3 ggrid(N_NODES / 128, 4);
    gru_gemm<128, true><<<ggrid, 256, 0, stream>>>(x,  PWF1, bi_f1, bh_f1, h1, 0);
    gru_gemm<128, true><<<ggrid, 256, 0, stream>>>(x,  PWB1, bi_b1, bh_b1, h1, 128);
    gru_gemm<256, false><<<ggrid, 256, 0, stream>>>(h1, PWF2, bi_f2, bh_f2, h2, 0);
    gru_gemm<256, false><<<ggrid, 256, 0, stream>>>(h1, PWB2, bi_b2, bh_b2, h2, 128);

    gemm_bt<256><<<dim3(N_NODES / 128, 2), 256, 0, stream>>>(h2, WT1, xw1, 128);
    stencil128<<<N_NODES * 128 / 256, 256, 0, stream>>>(xw1, b_g1, g1);
    gemm_bt<128><<<dim3(N_NODES / 128, 1), 256, 0, stream>>>(g1, WT2, xw2, 64);
    final_fc<<<N_NODES / 256, 256, 0, stream>>>(xw2, b_g2, w_fc, b_fc, (float*)d_out);
}

// Round 4
// 489.268 us; speedup vs baseline: 1.1973x; 1.1973x over previous
//
#include <hip/hip_runtime.h>
#include <stdint.h>

#define N_NODES 131072
#define HDIM 128

typedef __bf16 bf16x8 __attribute__((ext_vector_type(8)));
typedef float f32x4 __attribute__((ext_vector_type(4)));
typedef unsigned short us8 __attribute__((ext_vector_type(8)));
typedef unsigned short ushort_t;

__device__ __forceinline__ float bf2f(ushort_t u) {
    union { float f; uint32_t i; } v; v.i = ((uint32_t)u) << 16; return v.f;
}
__device__ __forceinline__ ushort_t f2bf(float f) {
    union { float f; uint32_t i; } v; v.f = f;
    uint32_t i = v.i;
    return (ushort_t)((i + 0x7FFFu + ((i >> 16) & 1u)) >> 16);  // RNE
}

// async global->LDS 16B DMA: LDS dest = wave-uniform base + lane*16
__device__ __forceinline__ void gll16(const ushort_t* g, ushort_t* l) {
    __builtin_amdgcn_global_load_lds(
        (const __attribute__((address_space(1))) uint32_t*)g,
        (__attribute__((address_space(3))) uint32_t*)l, 16, 0, 0);
}

// ---------------------------------------------------------------------------
// prep: fp32->bf16 weight conversion (+ transpose for GCN weights)
// ---------------------------------------------------------------------------
__global__ __launch_bounds__(256) void prep_weights(
    const float* __restrict__ w_f1, const float* __restrict__ w_b1,
    const float* __restrict__ w_f2, const float* __restrict__ w_b2,
    const float* __restrict__ w_g1, const float* __restrict__ w_g2,
    ushort_t* __restrict__ PWF1, ushort_t* __restrict__ PWB1,
    ushort_t* __restrict__ PWF2, ushort_t* __restrict__ PWB2,
    ushort_t* __restrict__ WT1,  ushort_t* __restrict__ WT2)
{
    int idx = blockIdx.x * 256 + threadIdx.x;
    if (idx < 49152) {
        PWF1[idx] = f2bf(w_f1[idx]);
    } else if (idx < 98304) {
        int j = idx - 49152;  PWB1[j] = f2bf(w_b1[j]);
    } else if (idx < 196608) {
        int j = idx - 98304;  PWF2[j] = f2bf(w_f2[j]);
    } else if (idx < 294912) {
        int j = idx - 196608; PWB2[j] = f2bf(w_b2[j]);
    } else if (idx < 327680) {
        int j = idx - 294912; int k = j >> 7, o = j & 127;   // w_g1 [256,128]
        WT1[o * 256 + k] = f2bf(w_g1[j]);                    // WT1 [128,256]
    } else if (idx < 335872) {
        int j = idx - 327680; int k = j >> 6, o = j & 63;    // w_g2 [128,64]
        WT2[o * 128 + k] = f2bf(w_g2[j]);                    // WT2 [64,128]
    }
}

// x fp32 [N,128] -> bf16, 8 elems/thread
__global__ __launch_bounds__(256) void xconv(
    const float* __restrict__ x, ushort_t* __restrict__ xb)
{
    int idx = blockIdx.x * 256 + threadIdx.x;   // N*16 chunks
    const float* s = x + (size_t)idx * 8;
    float4 f0 = ((const float4*)s)[0];
    float4 f1 = ((const float4*)s)[1];
    us8 t;
    t[0] = f2bf(f0.x); t[1] = f2bf(f0.y); t[2] = f2bf(f0.z); t[3] = f2bf(f0.w);
    t[4] = f2bf(f1.x); t[5] = f2bf(f1.y); t[6] = f2bf(f1.z); t[7] = f2bf(f1.w);
    *(us8*)&xb[(size_t)idx * 8] = t;
}

// ---------------------------------------------------------------------------
// Fused GRU GEMM (both directions in one launch), bf16 A, async LDS staging.
// grid (8, N/128): x = dir*4 + jtile (adjacent blocks share the A tile -> L2),
// tile: 128 rows x 32 j-cols x 3 gate strips, BK=128.
// ---------------------------------------------------------------------------
template<int K>
__global__ __launch_bounds__(256) void gru_gemm2(
    const ushort_t* __restrict__ A,      // [N,K] bf16
    const ushort_t* __restrict__ Wf,     // [384,K] bf16
    const ushort_t* __restrict__ Wb,     // [384,K] bf16
    const float* __restrict__ bi_f, const float* __restrict__ bh_f,
    const float* __restrict__ bi_b, const float* __restrict__ bh_b,
    ushort_t* __restrict__ Hout)         // [N,256] bf16
{
    __shared__ ushort_t As[128 * 128];   // unpadded: lane-ordered for global_load_lds
    __shared__ ushort_t Bs[96 * 128];
    const int tid = threadIdx.x;
    const int comb = blockIdx.x;         // 0..7
    const int dir = comb >> 2;
    const int j0 = (comb & 3) * 32;
    const int m0 = blockIdx.y * 128;
    const ushort_t* W = dir ? Wb : Wf;
    const float* b_ih = dir ? bi_b : bi_f;
    const float* b_hh = dir ? bh_b : bh_f;
    const int coloff = dir << 7;

    const int wv = tid >> 6, lane = tid & 63;
    const int lr = lane & 15, lq = lane >> 4;
    const int tr = tid >> 4, tc = tid & 15;
    const int wbase = tid & 192;         // 64*wave, wave-uniform

    f32x4 acc[3][2][2];
    #pragma unroll
    for (int g = 0; g < 3; ++g)
        #pragma unroll
        for (int rt = 0; rt < 2; ++rt)
            #pragma unroll
            for (int ct = 0; ct < 2; ++ct)
                #pragma unroll
                for (int e = 0; e < 4; ++e) acc[g][rt][ct][e] = 0.0f;

    for (int t = 0; t < K / 128; ++t) {
        const int k0 = t * 128;
        // A tile 128x128: 2048 chunks of 16B, 8 per thread
        const ushort_t* ga = A + (size_t)(m0 + tr) * K + k0 + tc * 8;
        #pragma unroll
        for (int i = 0; i < 8; ++i)
            gll16(ga + (size_t)i * 16 * K, &As[(i * 256 + wbase) * 8]);
        // B tile 96x128: 1536 chunks, 6 per thread
        #pragma unroll
        for (int i = 0; i < 6; ++i) {
            int row = i * 16 + tr;                       // 0..95
            int wr = ((row >> 5) << 7) + j0 + (row & 31);
            gll16(W + (size_t)wr * K + k0 + tc * 8, &Bs[(i * 256 + wbase) * 8]);
        }
        __syncthreads();                                  // drains vmcnt
        #pragma unroll
        for (int kk = 0; kk < 128; kk += 32) {
            const int ko = kk + lq * 8;
            bf16x8 a0 = *(const bf16x8*)&As[(wv * 32 + lr) * 128 + ko];
            bf16x8 a1 = *(const bf16x8*)&As[(wv * 32 + 16 + lr) * 128 + ko];
            #pragma unroll
            for (int g = 0; g < 3; ++g) {
                #pragma unroll
                for (int ct = 0; ct < 2; ++ct) {
                    bf16x8 b = *(const bf16x8*)&Bs[(g * 32 + ct * 16 + lr) * 128 + ko];
                    acc[g][0][ct] = __builtin_amdgcn_mfma_f32_16x16x32_bf16(a0, b, acc[g][0][ct], 0, 0, 0);
                    acc[g][1][ct] = __builtin_amdgcn_mfma_f32_16x16x32_bf16(a1, b, acc[g][1][ct], 0, 0, 0);
                }
            }
        }
        __syncthreads();
    }

    // epilogue: C/D layout col=lane&15, row=(lane>>4)*4+reg [m89/m91]
    #pragma unroll
    for (int ct = 0; ct < 2; ++ct) {
        const int j = j0 + ct * 16 + lr;
        const float br  = b_ih[j] + b_hh[j];
        const float bz  = b_ih[HDIM + j] + b_hh[HDIM + j];
        const float bn  = b_ih[2 * HDIM + j];
        const float bhn = b_hh[2 * HDIM + j];
        #pragma unroll
        for (int rt = 0; rt < 2; ++rt) {
            #pragma unroll
            for (int r = 0; r < 4; ++r) {
                const int row = m0 + wv * 32 + rt * 16 + lq * 4 + r;
                float ir = acc[0][rt][ct][r] + br;
                float iz = acc[1][rt][ct][r] + bz;
                float rg = 1.0f / (1.0f + expf(-ir));
                float zg = 1.0f / (1.0f + expf(-iz));
                float ng = tanhf(acc[2][rt][ct][r] + bn + rg * bhn);
                Hout[(size_t)row * 256 + coloff + j] = f2bf((1.0f - zg) * ng);
            }
        }
    }
}

// ---------------------------------------------------------------------------
// Plain GEMM Out = A @ Wt^T, async LDS staging. Tile 128x64, BK=128.
// grid (Nld/64, N/128)
// ---------------------------------------------------------------------------
template<int K>
__global__ __launch_bounds__(256) void gemm_bt2(
    const ushort_t* __restrict__ A,   // [N,K] bf16
    const ushort_t* __restrict__ Wt,  // [Nout,K] bf16
    ushort_t* __restrict__ Out,       // [N,Nld] bf16
    int Nld)
{
    __shared__ ushort_t As[128 * 128];
    __shared__ ushort_t Bs[64 * 128];
    const int tid = threadIdx.x;
    const int n0 = blockIdx.x * 64;
    const int m0 = blockIdx.y * 128;
    const int wv = tid >> 6, lane = tid & 63;
    const int lr = lane & 15, lq = lane >> 4;
    const int tr = tid >> 4, tc = tid & 15;
    const int wbase = tid & 192;

    f32x4 acc[2][4];
    #pragma unroll
    for (int rt = 0; rt < 2; ++rt)
        #pragma unroll
        for (int ct = 0; ct < 4; ++ct)
            #pragma unroll
            for (int e = 0; e < 4; ++e) acc[rt][ct][e] = 0.0f;

    for (int t = 0; t < K / 128; ++t) {
        const int k0 = t * 128;
        const ushort_t* ga = A + (size_t)(m0 + tr) * K + k0 + tc * 8;
        #pragma unroll
        for (int i = 0; i < 8; ++i)
            gll16(ga + (size_t)i * 16 * K, &As[(i * 256 + wbase) * 8]);
        const ushort_t* gb = Wt + (size_t)(n0 + tr) * K + k0 + tc * 8;
        #pragma unroll
        for (int i = 0; i < 4; ++i)
            gll16(gb + (size_t)i * 16 * K, &Bs[(i * 256 + wbase) * 8]);
        __syncthreads();
        #pragma unroll
        for (int kk = 0; kk < 128; kk += 32) {
            const int ko = kk + lq * 8;
            bf16x8 a0 = *(const bf16x8*)&As[(wv * 32 + lr) * 128 + ko];
            bf16x8 a1 = *(const bf16x8*)&As[(wv * 32 + 16 + lr) * 128 + ko];
            #pragma unroll
            for (int ct = 0; ct < 4; ++ct) {
                bf16x8 b = *(const bf16x8*)&Bs[(ct * 16 + lr) * 128 + ko];
                acc[0][ct] = __builtin_amdgcn_mfma_f32_16x16x32_bf16(a0, b, acc[0][ct], 0, 0, 0);
                acc[1][ct] = __builtin_amdgcn_mfma_f32_16x16x32_bf16(a1, b, acc[1][ct], 0, 0, 0);
            }
        }
        __syncthreads();
    }

    #pragma unroll
    for (int ct = 0; ct < 4; ++ct) {
        const int col = n0 + ct * 16 + lr;
        #pragma unroll
        for (int rt = 0; rt < 2; ++rt) {
            #pragma unroll
            for (int r = 0; r < 4; ++r) {
                const int row = m0 + wv * 32 + rt * 16 + lq * 4 + r;
                Out[(size_t)row * Nld + col] = f2bf(acc[rt][ct][r]);
            }
        }
    }
}

// ---------------------------------------------------------------------------
// GCN chain aggregation, vectorized 8 cols/thread:
// g[i] = di*(dm*x[i-1]+di*x[i]+dp*x[i+1]) + b
// ---------------------------------------------------------------------------
__global__ __launch_bounds__(256) void stencil8(
    const ushort_t* __restrict__ xw, const float* __restrict__ bias,
    ushort_t* __restrict__ g)
{
    const float S2 = 0.70710678118654752f, S3 = 0.57735026918962576f;
    int idx = blockIdx.x * 256 + threadIdx.x;   // N*16 chunks
    int i = idx >> 4, c8 = (idx & 15) << 3;
    float di = (i == 0 || i == N_NODES - 1) ? S2 : S3;
    bool hm = i > 0, hp = i < N_NODES - 1;
    float dm = hm ? ((i - 1 == 0) ? S2 : S3) : 0.0f;
    float dp = hp ? ((i + 1 == N_NODES - 1) ? S2 : S3) : 0.0f;
    const ushort_t* r0 = xw + (size_t)i * 128 + c8;
    const ushort_t* rm = xw + (size_t)(hm ? i - 1 : i) * 128 + c8;
    const ushort_t* rp = xw + (size_t)(hp ? i + 1 : i) * 128 + c8;
    us8 v0 = *(const us8*)r0;
    us8 vm = *(const us8*)rm;
    us8 vp = *(const us8*)rp;
    us8 o;
    #pragma unroll
    for (int e = 0; e < 8; ++e) {
        float s = di * bf2f(v0[e]) + dm * bf2f(vm[e]) + dp * bf2f(vp[e]);
        o[e] = f2bf(di * s + bias[c8 + e]);
    }
    *(us8*)&g[(size_t)i * 128 + c8] = o;
}

// ---------------------------------------------------------------------------
// Final: GCN2 aggregation (C=64) + bias + FC [64->10] + bias. fp32 out.
// ---------------------------------------------------------------------------
__global__ __launch_bounds__(256) void final_fc(
    const ushort_t* __restrict__ xw2,   // [N,64] bf16
    const float* __restrict__ b_g2,     // [64]
    const float* __restrict__ w_fc,     // [64,10]
    const float* __restrict__ b_fc,     // [10]
    float* __restrict__ out)            // [N,10] fp32
{
    __shared__ float wfc_s[640];
    __shared__ float bg2_s[64];
    __shared__ float bfc_s[10];
    const int tid = threadIdx.x;
    for (int t = tid; t < 640; t += 256) wfc_s[t] = w_fc[t];
    if (tid < 64) bg2_s[tid] = b_g2[tid];
    if (tid < 10) bfc_s[tid] = b_fc[tid];
    __syncthreads();

    const float S2 = 0.70710678118654752f, S3 = 0.57735026918962576f;
    const int i = blockIdx.x * 256 + tid;
    float di = (i == 0 || i == N_NODES - 1) ? S2 : S3;
    bool hm = i > 0, hp = i < N_NODES - 1;
    float dm = hm ? ((i - 1 == 0) ? S2 : S3) : 0.0f;
    float dp = hp ? ((i + 1 == N_NODES - 1) ? S2 : S3) : 0.0f;
    const ushort_t* r0 = xw2 + (size_t)i * 64;
    const ushort_t* rm = xw2 + (size_t)(hm ? i - 1 : i) * 64;
    const ushort_t* rp = xw2 + (size_t)(hp ? i + 1 : i) * 64;

    float o[10];
    #pragma unroll
    for (int k = 0; k < 10; ++k) o[k] = bfc_s[k];
    #pragma unroll
    for (int c8 = 0; c8 < 8; ++c8) {
        us8 v0 = *(const us8*)&r0[c8 * 8];
        us8 vm = *(const us8*)&rm[c8 * 8];
        us8 vp = *(const us8*)&rp[c8 * 8];
        #pragma unroll
        for (int e = 0; e < 8; ++e) {
            int c = c8 * 8 + e;
            float s = di * bf2f(v0[e]) + dm * bf2f(vm[e]) + dp * bf2f(vp[e]);
            float g2 = di * s + bg2_s[c];
            #pragma unroll
            for (int k = 0; k < 10; ++k) o[k] += g2 * wfc_s[c * 10 + k];
        }
    }
    #pragma unroll
    for (int k = 0; k < 10; ++k) out[(size_t)i * 10 + k] = o[k];
}

extern "C" void kernel_launch(void* const* d_in, const int* in_sizes, int n_in,
                              void* d_out, int out_size, void* d_ws, size_t ws_size,
                              hipStream_t stream) {
    const float* x     = (const float*)d_in[0];
    const float* w_f1  = (const float*)d_in[1];
    const float* bi_f1 = (const float*)d_in[2];
    const float* bh_f1 = (const float*)d_in[3];
    const float* w_b1  = (const float*)d_in[4];
    const float* bi_b1 = (const float*)d_in[5];
    const float* bh_b1 = (const float*)d_in[6];
    const float* w_f2  = (const float*)d_in[7];
    const float* bi_f2 = (const float*)d_in[8];
    const float* bh_f2 = (const float*)d_in[9];
    const float* w_b2  = (const float*)d_in[10];
    const float* bi_b2 = (const float*)d_in[11];
    const float* bh_b2 = (const float*)d_in[12];
    const float* w_g1  = (const float*)d_in[13];
    const float* b_g1  = (const float*)d_in[14];
    const float* w_g2  = (const float*)d_in[15];
    const float* b_g2  = (const float*)d_in[16];
    const float* w_fc  = (const float*)d_in[17];
    const float* b_fc  = (const float*)d_in[18];

    char* ws = (char*)d_ws;
    // peak 134.9 MB (same as validated round 3):
    ushort_t* h1   = (ushort_t*)(ws);                    // [N,256] (67.1MB), dies after layer2
    ushort_t* xb   = (ushort_t*)(ws + 67108864);         // [N,128] bf16 x, dies after layer1
    ushort_t* h2   = (ushort_t*)(ws + 67108864);         // [N,256], overwrites dead xb
    ushort_t* xw1  = (ushort_t*)(ws);                    // [N,128], reuse dead h1
    ushort_t* g1   = (ushort_t*)(ws + 33554432);         // [N,128]
    ushort_t* xw2  = (ushort_t*)(ws + 67108864);         // [N,64], reuse dead h2
    ushort_t* PWF1 = (ushort_t*)(ws + 134217728);        // [384,128]
    ushort_t* PWB1 = PWF1 + 49152;
    ushort_t* PWF2 = PWB1 + 49152;                       // [384,256]
    ushort_t* PWB2 = PWF2 + 98304;
    ushort_t* WT1  = PWB2 + 98304;                       // [128,256]
    ushort_t* WT2  = WT1 + 32768;                        // [64,128]

    prep_weights<<<1312, 256, 0, stream>>>(w_f1, w_b1, w_f2, w_b2, w_g1, w_g2,
                                           PWF1, PWB1, PWF2, PWB2, WT1, WT2);
    xconv<<<N_NODES * 16 / 256, 256, 0, stream>>>(x, xb);

    gru_gemm2<128><<<dim3(8, N_NODES / 128), 256, 0, stream>>>(
        xb, PWF1, PWB1, bi_f1, bh_f1, bi_b1, bh_b1, h1);
    gru_gemm2<256><<<dim3(8, N_NODES / 128), 256, 0, stream>>>(
        h1, PWF2, PWB2, bi_f2, bh_f2, bi_b2, bh_b2, h2);

    gemm_bt2<256><<<dim3(2, N_NODES / 128), 256, 0, stream>>>(h2, WT1, xw1, 128);
    stencil8<<<N_NODES * 16 / 256, 256, 0, stream>>>(xw1, b_g1, g1);
    gemm_bt2<128><<<dim3(1, N_NODES / 128), 256, 0, stream>>>(g1, WT2, xw2, 64);
    final_fc<<<N_NODES / 256, 256, 0, stream>>>(xw2, b_g2, w_fc, b_fc, (float*)d_out);
}

// Round 5
// 356.064 us; speedup vs baseline: 1.6452x; 1.3741x over previous
//
#include <hip/hip_runtime.h>
#include <stdint.h>

#define N_NODES 131072
#define HDIM 128

typedef __bf16 bf16x8 __attribute__((ext_vector_type(8)));
typedef float f32x4 __attribute__((ext_vector_type(4)));
typedef unsigned short us8 __attribute__((ext_vector_type(8)));
typedef unsigned short ushort_t;

__device__ __forceinline__ float bf2f(ushort_t u) {
    union { float f; uint32_t i; } v; v.i = ((uint32_t)u) << 16; return v.f;
}
__device__ __forceinline__ ushort_t f2bf(float f) {
    union { float f; uint32_t i; } v; v.f = f;
    uint32_t i = v.i;
    return (ushort_t)((i + 0x7FFFu + ((i >> 16) & 1u)) >> 16);  // RNE
}

// async global->LDS 16B DMA: LDS dest = wave-uniform base + lane*16
__device__ __forceinline__ void gll16(const ushort_t* g, ushort_t* l) {
    __builtin_amdgcn_global_load_lds(
        (const __attribute__((address_space(1))) uint32_t*)g,
        (__attribute__((address_space(3))) uint32_t*)l, 16, 0, 0);
}

// swizzled LDS fragment read: LDS[r][c] holds G[r][(c+r)&15] (16B chunks)
__device__ __forceinline__ bf16x8 ldsw(const ushort_t* base, int R, int g) {
    return *(const bf16x8*)&base[R * 128 + (((g - R) & 15) << 3)];
}

// fast sigmoid / tanh via v_exp_f32 + v_rcp_f32 (bf16-accurate)
__device__ __forceinline__ float fsig(float x) {
    return __builtin_amdgcn_rcpf(1.0f + __expf(-x));
}
__device__ __forceinline__ float ftanh(float y) {
    float yc = fminf(fmaxf(y, -15.0f), 15.0f);
    float e = __expf(2.0f * yc);
    return (e - 1.0f) * __builtin_amdgcn_rcpf(e + 1.0f);
}

// ---------------------------------------------------------------------------
// prep: fp32->bf16 weight conversion (+ transpose for GCN weights)
// ---------------------------------------------------------------------------
__global__ __launch_bounds__(256) void prep_weights(
    const float* __restrict__ w_f1, const float* __restrict__ w_b1,
    const float* __restrict__ w_f2, const float* __restrict__ w_b2,
    const float* __restrict__ w_g1, const float* __restrict__ w_g2,
    ushort_t* __restrict__ PWF1, ushort_t* __restrict__ PWB1,
    ushort_t* __restrict__ PWF2, ushort_t* __restrict__ PWB2,
    ushort_t* __restrict__ WT1,  ushort_t* __restrict__ WT2)
{
    int idx = blockIdx.x * 256 + threadIdx.x;
    if (idx < 49152) {
        PWF1[idx] = f2bf(w_f1[idx]);
    } else if (idx < 98304) {
        int j = idx - 49152;  PWB1[j] = f2bf(w_b1[j]);
    } else if (idx < 196608) {
        int j = idx - 98304;  PWF2[j] = f2bf(w_f2[j]);
    } else if (idx < 294912) {
        int j = idx - 196608; PWB2[j] = f2bf(w_b2[j]);
    } else if (idx < 327680) {
        int j = idx - 294912; int k = j >> 7, o = j & 127;   // w_g1 [256,128]
        WT1[o * 256 + k] = f2bf(w_g1[j]);                    // WT1 [128,256]
    } else if (idx < 335872) {
        int j = idx - 327680; int k = j >> 6, o = j & 63;    // w_g2 [128,64]
        WT2[o * 128 + k] = f2bf(w_g2[j]);                    // WT2 [64,128]
    }
}

// x fp32 [N,128] -> bf16, 8 elems/thread
__global__ __launch_bounds__(256) void xconv(
    const float* __restrict__ x, ushort_t* __restrict__ xb)
{
    int idx = blockIdx.x * 256 + threadIdx.x;   // N*16 chunks
    const float* s = x + (size_t)idx * 8;
    float4 f0 = ((const float4*)s)[0];
    float4 f1 = ((const float4*)s)[1];
    us8 t;
    t[0] = f2bf(f0.x); t[1] = f2bf(f0.y); t[2] = f2bf(f0.z); t[3] = f2bf(f0.w);
    t[4] = f2bf(f1.x); t[5] = f2bf(f1.y); t[6] = f2bf(f1.z); t[7] = f2bf(f1.w);
    *(us8*)&xb[(size_t)idx * 8] = t;
}

// ---------------------------------------------------------------------------
// Fused GRU GEMM (both directions), bf16 A, async LDS staging + rot swizzle.
// grid (N/128, 8): y = dir*4 + jtile; all 8 combos of one m-tile have linear
// ids m + 1024*y == m (mod 8) -> SAME XCD -> A-tile fetched ~once per tile.
// ---------------------------------------------------------------------------
template<int K>
__global__ __launch_bounds__(256) void gru_gemm2(
    const ushort_t* __restrict__ A,      // [N,K] bf16
    const ushort_t* __restrict__ Wf,     // [384,K] bf16
    const ushort_t* __restrict__ Wb,     // [384,K] bf16
    const float* __restrict__ bi_f, const float* __restrict__ bh_f,
    const float* __restrict__ bi_b, const float* __restrict__ bh_b,
    ushort_t* __restrict__ Hout)         // [N,256] bf16
{
    __shared__ ushort_t As[128 * 128];
    __shared__ ushort_t Bs[96 * 128];
    const int tid = threadIdx.x;
    const int m0 = blockIdx.x * 128;
    const int comb = blockIdx.y;         // 0..7
    const int dir = comb >> 2;
    const int j0 = (comb & 3) * 32;
    const ushort_t* W = dir ? Wb : Wf;
    const float* b_ih = dir ? bi_b : bi_f;
    const float* b_hh = dir ? bh_b : bh_f;
    const int coloff = dir << 7;

    const int wv = tid >> 6, lane = tid & 63;
    const int lr = lane & 15, lq = lane >> 4;
    const int tr = tid >> 4, tc = tid & 15;
    const int sc = ((tr + tc) & 15) << 3;   // rotated source chunk (shorts)
    const int wbase = tid & 192;            // 64*wave, wave-uniform

    f32x4 acc[3][2][2];
    #pragma unroll
    for (int g = 0; g < 3; ++g)
        #pragma unroll
        for (int rt = 0; rt < 2; ++rt)
            #pragma unroll
            for (int ct = 0; ct < 2; ++ct)
                #pragma unroll
                for (int e = 0; e < 4; ++e) acc[g][rt][ct][e] = 0.0f;

    for (int t = 0; t < K / 128; ++t) {
        const int k0 = t * 128;
        // A tile 128x128, rotated: LDS row r holds chunks (c+r)&15
        const ushort_t* ga = A + (size_t)(m0 + tr) * K + k0 + sc;
        #pragma unroll
        for (int i = 0; i < 8; ++i)
            gll16(ga + (size_t)i * 16 * K, &As[(i * 256 + wbase) * 8]);
        // B tile 96x128 (3 gate strips x 32 rows), rotated
        #pragma unroll
        for (int i = 0; i < 6; ++i) {
            int row = i * 16 + tr;                       // 0..95
            int wr = ((row >> 5) << 7) + j0 + (row & 31);
            gll16(W + (size_t)wr * K + k0 + sc, &Bs[(i * 256 + wbase) * 8]);
        }
        __syncthreads();
        #pragma unroll
        for (int kk = 0; kk < 128; kk += 32) {
            const int g8 = (kk >> 3) + lq;
            bf16x8 a0 = ldsw(As, wv * 32 + lr, g8);
            bf16x8 a1 = ldsw(As, wv * 32 + 16 + lr, g8);
            #pragma unroll
            for (int g = 0; g < 3; ++g) {
                #pragma unroll
                for (int ct = 0; ct < 2; ++ct) {
                    bf16x8 b = ldsw(Bs, g * 32 + ct * 16 + lr, g8);
                    acc[g][0][ct] = __builtin_amdgcn_mfma_f32_16x16x32_bf16(a0, b, acc[g][0][ct], 0, 0, 0);
                    acc[g][1][ct] = __builtin_amdgcn_mfma_f32_16x16x32_bf16(a1, b, acc[g][1][ct], 0, 0, 0);
                }
            }
        }
        __syncthreads();
    }

    // epilogue: C/D layout col=lane&15, row=(lane>>4)*4+reg [m89/m91]
    #pragma unroll
    for (int ct = 0; ct < 2; ++ct) {
        const int j = j0 + ct * 16 + lr;
        const float br  = b_ih[j] + b_hh[j];
        const float bz  = b_ih[HDIM + j] + b_hh[HDIM + j];
        const float bn  = b_ih[2 * HDIM + j];
        const float bhn = b_hh[2 * HDIM + j];
        #pragma unroll
        for (int rt = 0; rt < 2; ++rt) {
            #pragma unroll
            for (int r = 0; r < 4; ++r) {
                const int row = m0 + wv * 32 + rt * 16 + lq * 4 + r;
                float rg = fsig(acc[0][rt][ct][r] + br);
                float zg = fsig(acc[1][rt][ct][r] + bz);
                float ng = ftanh(acc[2][rt][ct][r] + bn + rg * bhn);
                Hout[(size_t)row * 256 + coloff + j] = f2bf((1.0f - zg) * ng);
            }
        }
    }
}

// ---------------------------------------------------------------------------
// Plain GEMM Out = A @ Wt^T, async staging + rot swizzle. Tile 128x64, BK=128.
// grid (N/128, Nld/64): n-tiles of one m-tile co-XCD.
// ---------------------------------------------------------------------------
template<int K>
__global__ __launch_bounds__(256) void gemm_bt2(
    const ushort_t* __restrict__ A,   // [N,K] bf16
    const ushort_t* __restrict__ Wt,  // [Nout,K] bf16
    ushort_t* __restrict__ Out,       // [N,Nld] bf16
    int Nld)
{
    __shared__ ushort_t As[128 * 128];
    __shared__ ushort_t Bs[64 * 128];
    const int tid = threadIdx.x;
    const int m0 = blockIdx.x * 128;
    const int n0 = blockIdx.y * 64;
    const int wv = tid >> 6, lane = tid & 63;
    const int lr = lane & 15, lq = lane >> 4;
    const int tr = tid >> 4, tc = tid & 15;
    const int sc = ((tr + tc) & 15) << 3;
    const int wbase = tid & 192;

    f32x4 acc[2][4];
    #pragma unroll
    for (int rt = 0; rt < 2; ++rt)
        #pragma unroll
        for (int ct = 0; ct < 4; ++ct)
            #pragma unroll
            for (int e = 0; e < 4; ++e) acc[rt][ct][e] = 0.0f;

    for (int t = 0; t < K / 128; ++t) {
        const int k0 = t * 128;
        const ushort_t* ga = A + (size_t)(m0 + tr) * K + k0 + sc;
        #pragma unroll
        for (int i = 0; i < 8; ++i)
            gll16(ga + (size_t)i * 16 * K, &As[(i * 256 + wbase) * 8]);
        const ushort_t* gb = Wt + (size_t)(n0 + tr) * K + k0 + sc;
        #pragma unroll
        for (int i = 0; i < 4; ++i)
            gll16(gb + (size_t)i * 16 * K, &Bs[(i * 256 + wbase) * 8]);
        __syncthreads();
        #pragma unroll
        for (int kk = 0; kk < 128; kk += 32) {
            const int g8 = (kk >> 3) + lq;
            bf16x8 a0 = ldsw(As, wv * 32 + lr, g8);
            bf16x8 a1 = ldsw(As, wv * 32 + 16 + lr, g8);
            #pragma unroll
            for (int ct = 0; ct < 4; ++ct) {
                bf16x8 b = ldsw(Bs, ct * 16 + lr, g8);
                acc[0][ct] = __builtin_amdgcn_mfma_f32_16x16x32_bf16(a0, b, acc[0][ct], 0, 0, 0);
                acc[1][ct] = __builtin_amdgcn_mfma_f32_16x16x32_bf16(a1, b, acc[1][ct], 0, 0, 0);
            }
        }
        __syncthreads();
    }

    #pragma unroll
    for (int ct = 0; ct < 4; ++ct) {
        const int col = n0 + ct * 16 + lr;
        #pragma unroll
        for (int rt = 0; rt < 2; ++rt) {
            #pragma unroll
            for (int r = 0; r < 4; ++r) {
                const int row = m0 + wv * 32 + rt * 16 + lq * 4 + r;
                Out[(size_t)row * Nld + col] = f2bf(acc[rt][ct][r]);
            }
        }
    }
}

// ---------------------------------------------------------------------------
// GCN chain aggregation, 8 cols/thread: g[i]=di*(dm*x[i-1]+di*x[i]+dp*x[i+1])+b
// ---------------------------------------------------------------------------
__global__ __launch_bounds__(256) void stencil8(
    const ushort_t* __restrict__ xw, const float* __restrict__ bias,
    ushort_t* __restrict__ g)
{
    const float S2 = 0.70710678118654752f, S3 = 0.57735026918962576f;
    int idx = blockIdx.x * 256 + threadIdx.x;   // N*16 chunks
    int i = idx >> 4, c8 = (idx & 15) << 3;
    float di = (i == 0 || i == N_NODES - 1) ? S2 : S3;
    bool hm = i > 0, hp = i < N_NODES - 1;
    float dm = hm ? ((i - 1 == 0) ? S2 : S3) : 0.0f;
    float dp = hp ? ((i + 1 == N_NODES - 1) ? S2 : S3) : 0.0f;
    us8 v0 = *(const us8*)(xw + (size_t)i * 128 + c8);
    us8 vm = *(const us8*)(xw + (size_t)(hm ? i - 1 : i) * 128 + c8);
    us8 vp = *(const us8*)(xw + (size_t)(hp ? i + 1 : i) * 128 + c8);
    us8 o;
    #pragma unroll
    for (int e = 0; e < 8; ++e) {
        float s = di * bf2f(v0[e]) + dm * bf2f(vm[e]) + dp * bf2f(vp[e]);
        o[e] = f2bf(di * s + bias[c8 + e]);
    }
    *(us8*)&g[(size_t)i * 128 + c8] = o;
}

// ---------------------------------------------------------------------------
// Final: GCN2 aggregation (C=64) + bias + FC [64->10] + bias. fp32 out.
// ---------------------------------------------------------------------------
__global__ __launch_bounds__(256) void final_fc(
    const ushort_t* __restrict__ xw2,   // [N,64] bf16
    const float* __restrict__ b_g2,     // [64]
    const float* __restrict__ w_fc,     // [64,10]
    const float* __restrict__ b_fc,     // [10]
    float* __restrict__ out)            // [N,10] fp32
{
    __shared__ float wfc_s[640];
    __shared__ float bg2_s[64];
    __shared__ float bfc_s[10];
    const int tid = threadIdx.x;
    for (int t = tid; t < 640; t += 256) wfc_s[t] = w_fc[t];
    if (tid < 64) bg2_s[tid] = b_g2[tid];
    if (tid < 10) bfc_s[tid] = b_fc[tid];
    __syncthreads();

    const float S2 = 0.70710678118654752f, S3 = 0.57735026918962576f;
    const int i = blockIdx.x * 256 + tid;
    float di = (i == 0 || i == N_NODES - 1) ? S2 : S3;
    bool hm = i > 0, hp = i < N_NODES - 1;
    float dm = hm ? ((i - 1 == 0) ? S2 : S3) : 0.0f;
    float dp = hp ? ((i + 1 == N_NODES - 1) ? S2 : S3) : 0.0f;
    const ushort_t* r0 = xw2 + (size_t)i * 64;
    const ushort_t* rm = xw2 + (size_t)(hm ? i - 1 : i) * 64;
    const ushort_t* rp = xw2 + (size_t)(hp ? i + 1 : i) * 64;

    float o[10];
    #pragma unroll
    for (int k = 0; k < 10; ++k) o[k] = bfc_s[k];
    #pragma unroll
    for (int c8 = 0; c8 < 8; ++c8) {
        us8 v0 = *(const us8*)&r0[c8 * 8];
        us8 vm = *(const us8*)&rm[c8 * 8];
        us8 vp = *(const us8*)&rp[c8 * 8];
        #pragma unroll
        for (int e = 0; e < 8; ++e) {
            int c = c8 * 8 + e;
            float s = di * bf2f(v0[e]) + dm * bf2f(vm[e]) + dp * bf2f(vp[e]);
            float g2 = di * s + bg2_s[c];
            #pragma unroll
            for (int k = 0; k < 10; ++k) o[k] += g2 * wfc_s[c * 10 + k];
        }
    }
    #pragma unroll
    for (int k = 0; k < 10; ++k) out[(size_t)i * 10 + k] = o[k];
}

extern "C" void kernel_launch(void* const* d_in, const int* in_sizes, int n_in,
                              void* d_out, int out_size, void* d_ws, size_t ws_size,
                              hipStream_t stream) {
    const float* x     = (const float*)d_in[0];
    const float* w_f1  = (const float*)d_in[1];
    const float* bi_f1 = (const float*)d_in[2];
    const float* bh_f1 = (const float*)d_in[3];
    const float* w_b1  = (const float*)d_in[4];
    const float* bi_b1 = (const float*)d_in[5];
    const float* bh_b1 = (const float*)d_in[6];
    const float* w_f2  = (const float*)d_in[7];
    const float* bi_f2 = (const float*)d_in[8];
    const float* bh_f2 = (const float*)d_in[9];
    const float* w_b2  = (const float*)d_in[10];
    const float* bi_b2 = (const float*)d_in[11];
    const float* bh_b2 = (const float*)d_in[12];
    const float* w_g1  = (const float*)d_in[13];
    const float* b_g1  = (const float*)d_in[14];
    const float* w_g2  = (const float*)d_in[15];
    const float* b_g2  = (const float*)d_in[16];
    const float* w_fc  = (const float*)d_in[17];
    const float* b_fc  = (const float*)d_in[18];

    char* ws = (char*)d_ws;
    ushort_t* h1   = (ushort_t*)(ws);                    // [N,256], dies after layer2
    ushort_t* xb   = (ushort_t*)(ws + 67108864);         // [N,128] bf16 x, dies after layer1
    ushort_t* h2   = (ushort_t*)(ws + 67108864);         // [N,256], overwrites dead xb
    ushort_t* xw1  = (ushort_t*)(ws);                    // [N,128], reuse dead h1
    ushort_t* g1   = (ushort_t*)(ws + 33554432);         // [N,128]
    ushort_t* xw2  = (ushort_t*)(ws + 67108864);         // [N,64], reuse dead h2
    ushort_t* PWF1 = (ushort_t*)(ws + 134217728);        // [384,128]
    ushort_t* PWB1 = PWF1 + 49152;
    ushort_t* PWF2 = PWB1 + 49152;                       // [384,256]
    ushort_t* PWB2 = PWF2 + 98304;
    ushort_t* WT1  = PWB2 + 98304;                       // [128,256]
    ushort_t* WT2  = WT1 + 32768;                        // [64,128]

    prep_weights<<<1312, 256, 0, stream>>>(w_f1, w_b1, w_f2, w_b2, w_g1, w_g2,
                                           PWF1, PWB1, PWF2, PWB2, WT1, WT2);
    xconv<<<N_NODES * 16 / 256, 256, 0, stream>>>(x, xb);

    gru_gemm2<128><<<dim3(N_NODES / 128, 8), 256, 0, stream>>>(
        xb, PWF1, PWB1, bi_f1, bh_f1, bi_b1, bh_b1, h1);
    gru_gemm2<256><<<dim3(N_NODES / 128, 8), 256, 0, stream>>>(
        h1, PWF2, PWB2, bi_f2, bh_f2, bi_b2, bh_b2, h2);

    gemm_bt2<256><<<dim3(N_NODES / 128, 2), 256, 0, stream>>>(h2, WT1, xw1, 128);
    stencil8<<<N_NODES * 16 / 256, 256, 0, stream>>>(xw1, b_g1, g1);
    gemm_bt2<128><<<dim3(N_NODES / 128, 1), 256, 0, stream>>>(g1, WT2, xw2, 64);
    final_fc<<<N_NODES / 256, 256, 0, stream>>>(xw2, b_g2, w_fc, b_fc, (float*)d_out);
}

// Round 6
// 318.870 us; speedup vs baseline: 1.8371x; 1.1166x over previous
//
#include <hip/hip_runtime.h>
#include <stdint.h>

#define N_NODES 131072
#define HDIM 128

typedef __bf16 bf16x8 __attribute__((ext_vector_type(8)));
typedef float f32x4 __attribute__((ext_vector_type(4)));
typedef unsigned short us8 __attribute__((ext_vector_type(8)));
typedef unsigned short ushort_t;

__device__ __forceinline__ float bf2f(ushort_t u) {
    union { float f; uint32_t i; } v; v.i = ((uint32_t)u) << 16; return v.f;
}
__device__ __forceinline__ ushort_t f2bf(float f) {
    union { float f; uint32_t i; } v; v.f = f;
    uint32_t i = v.i;
    return (ushort_t)((i + 0x7FFFu + ((i >> 16) & 1u)) >> 16);  // RNE
}

// async global->LDS 16B DMA: LDS dest = wave-uniform base + lane*16
__device__ __forceinline__ void gll16(const ushort_t* g, ushort_t* l) {
    __builtin_amdgcn_global_load_lds(
        (const __attribute__((address_space(1))) uint32_t*)g,
        (__attribute__((address_space(3))) uint32_t*)l, 16, 0, 0);
}

// swizzled LDS fragment read: LDS[r][c] holds G[r][(c+r)&15] (16B chunks)
__device__ __forceinline__ bf16x8 ldsw(const ushort_t* base, int R, int g) {
    return *(const bf16x8*)&base[R * 128 + (((g - R) & 15) << 3)];
}

// fast sigmoid / tanh via v_exp_f32 + v_rcp_f32 (bf16-accurate)
__device__ __forceinline__ float fsig(float x) {
    return __builtin_amdgcn_rcpf(1.0f + __expf(-x));
}
__device__ __forceinline__ float ftanh(float y) {
    float yc = fminf(fmaxf(y, -15.0f), 15.0f);
    float e = __expf(2.0f * yc);
    return (e - 1.0f) * __builtin_amdgcn_rcpf(e + 1.0f);
}

// XCD-temporal block swizzle: 1D id b -> (m, c). The NC combos of one m-tile
// occupy ids mhi*(8*NC)+c*8+mlo: same (id mod 8) -> same XCD under round-robin,
// within an 8*NC-id window -> temporally co-resident -> A-tile L2 reuse.
template<int NC>
__device__ __forceinline__ void swz(int b, int& m, int& c) {
    int mhi = b / (8 * NC);
    int rem = b - mhi * (8 * NC);
    c = rem >> 3;
    m = mhi * 8 + (rem & 7);
}

// ---------------------------------------------------------------------------
// prep: fp32->bf16 weight conversion (+ transpose for GCN weights)
// ---------------------------------------------------------------------------
__global__ __launch_bounds__(256) void prep_weights(
    const float* __restrict__ w_f1, const float* __restrict__ w_b1,
    const float* __restrict__ w_f2, const float* __restrict__ w_b2,
    const float* __restrict__ w_g1, const float* __restrict__ w_g2,
    ushort_t* __restrict__ PWF1, ushort_t* __restrict__ PWB1,
    ushort_t* __restrict__ PWF2, ushort_t* __restrict__ PWB2,
    ushort_t* __restrict__ WT1,  ushort_t* __restrict__ WT2)
{
    int idx = blockIdx.x * 256 + threadIdx.x;
    if (idx < 49152) {
        PWF1[idx] = f2bf(w_f1[idx]);
    } else if (idx < 98304) {
        int j = idx - 49152;  PWB1[j] = f2bf(w_b1[j]);
    } else if (idx < 196608) {
        int j = idx - 98304;  PWF2[j] = f2bf(w_f2[j]);
    } else if (idx < 294912) {
        int j = idx - 196608; PWB2[j] = f2bf(w_b2[j]);
    } else if (idx < 327680) {
        int j = idx - 294912; int k = j >> 7, o = j & 127;   // w_g1 [256,128]
        WT1[o * 256 + k] = f2bf(w_g1[j]);                    // WT1 [128,256]
    } else if (idx < 335872) {
        int j = idx - 327680; int k = j >> 6, o = j & 63;    // w_g2 [128,64]
        WT2[o * 128 + k] = f2bf(w_g2[j]);                    // WT2 [64,128]
    }
}

// x fp32 [N,128] -> bf16, 8 elems/thread
__global__ __launch_bounds__(256) void xconv(
    const float* __restrict__ x, ushort_t* __restrict__ xb)
{
    int idx = blockIdx.x * 256 + threadIdx.x;   // N*16 chunks
    const float* s = x + (size_t)idx * 8;
    float4 f0 = ((const float4*)s)[0];
    float4 f1 = ((const float4*)s)[1];
    us8 t;
    t[0] = f2bf(f0.x); t[1] = f2bf(f0.y); t[2] = f2bf(f0.z); t[3] = f2bf(f0.w);
    t[4] = f2bf(f1.x); t[5] = f2bf(f1.y); t[6] = f2bf(f1.z); t[7] = f2bf(f1.w);
    *(us8*)&xb[(size_t)idx * 8] = t;
}

// ---------------------------------------------------------------------------
// Fused GRU GEMM (both directions), bf16 A, async LDS staging + rot swizzle.
// 1D grid 8*N/128 with XCD-temporal swizzle (8 combos/m-tile co-XCD+co-time).
// ---------------------------------------------------------------------------
template<int K>
__global__ __launch_bounds__(256) void gru_gemm2(
    const ushort_t* __restrict__ A,      // [N,K] bf16
    const ushort_t* __restrict__ Wf,     // [384,K] bf16
    const ushort_t* __restrict__ Wb,     // [384,K] bf16
    const float* __restrict__ bi_f, const float* __restrict__ bh_f,
    const float* __restrict__ bi_b, const float* __restrict__ bh_b,
    ushort_t* __restrict__ Hout)         // [N,256] bf16
{
    __shared__ ushort_t As[128 * 128];
    __shared__ ushort_t Bs[96 * 128];
    const int tid = threadIdx.x;
    int mt, comb;
    swz<8>(blockIdx.x, mt, comb);
    const int m0 = mt * 128;
    const int dir = comb >> 2;
    const int j0 = (comb & 3) * 32;
    const ushort_t* W = dir ? Wb : Wf;
    const float* b_ih = dir ? bi_b : bi_f;
    const float* b_hh = dir ? bh_b : bh_f;
    const int coloff = dir << 7;

    const int wv = tid >> 6, lane = tid & 63;
    const int lr = lane & 15, lq = lane >> 4;
    const int tr = tid >> 4, tc = tid & 15;
    const int sc = ((tr + tc) & 15) << 3;   // rotated source chunk (shorts)
    const int wbase = tid & 192;            // 64*wave, wave-uniform

    f32x4 acc[3][2][2];
    #pragma unroll
    for (int g = 0; g < 3; ++g)
        #pragma unroll
        for (int rt = 0; rt < 2; ++rt)
            #pragma unroll
            for (int ct = 0; ct < 2; ++ct)
                #pragma unroll
                for (int e = 0; e < 4; ++e) acc[g][rt][ct][e] = 0.0f;

    for (int t = 0; t < K / 128; ++t) {
        const int k0 = t * 128;
        // A tile 128x128, rotated: LDS row r holds chunks (c+r)&15
        const ushort_t* ga = A + (size_t)(m0 + tr) * K + k0 + sc;
        #pragma unroll
        for (int i = 0; i < 8; ++i)
            gll16(ga + (size_t)i * 16 * K, &As[(i * 256 + wbase) * 8]);
        // B tile 96x128 (3 gate strips x 32 rows), rotated
        #pragma unroll
        for (int i = 0; i < 6; ++i) {
            int row = i * 16 + tr;                       // 0..95
            int wr = ((row >> 5) << 7) + j0 + (row & 31);
            gll16(W + (size_t)wr * K + k0 + sc, &Bs[(i * 256 + wbase) * 8]);
        }
        __syncthreads();
        #pragma unroll
        for (int kk = 0; kk < 128; kk += 32) {
            const int g8 = (kk >> 3) + lq;
            bf16x8 a0 = ldsw(As, wv * 32 + lr, g8);
            bf16x8 a1 = ldsw(As, wv * 32 + 16 + lr, g8);
            #pragma unroll
            for (int g = 0; g < 3; ++g) {
                #pragma unroll
                for (int ct = 0; ct < 2; ++ct) {
                    bf16x8 b = ldsw(Bs, g * 32 + ct * 16 + lr, g8);
                    acc[g][0][ct] = __builtin_amdgcn_mfma_f32_16x16x32_bf16(a0, b, acc[g][0][ct], 0, 0, 0);
                    acc[g][1][ct] = __builtin_amdgcn_mfma_f32_16x16x32_bf16(a1, b, acc[g][1][ct], 0, 0, 0);
                }
            }
        }
        __syncthreads();
    }

    // epilogue: C/D layout col=lane&15, row=(lane>>4)*4+reg [m89/m91]
    #pragma unroll
    for (int ct = 0; ct < 2; ++ct) {
        const int j = j0 + ct * 16 + lr;
        const float br  = b_ih[j] + b_hh[j];
        const float bz  = b_ih[HDIM + j] + b_hh[HDIM + j];
        const float bn  = b_ih[2 * HDIM + j];
        const float bhn = b_hh[2 * HDIM + j];
        #pragma unroll
        for (int rt = 0; rt < 2; ++rt) {
            #pragma unroll
            for (int r = 0; r < 4; ++r) {
                const int row = m0 + wv * 32 + rt * 16 + lq * 4 + r;
                float rg = fsig(acc[0][rt][ct][r] + br);
                float zg = fsig(acc[1][rt][ct][r] + bz);
                float ng = ftanh(acc[2][rt][ct][r] + bn + rg * bhn);
                Hout[(size_t)row * 256 + coloff + j] = f2bf((1.0f - zg) * ng);
            }
        }
    }
}

// ---------------------------------------------------------------------------
// Plain GEMM Out = A @ Wt^T, async staging + rot swizzle. Tile 128x64, BK=128.
// 1D grid NC*N/128 with XCD-temporal swizzle.
// ---------------------------------------------------------------------------
template<int K, int NC>
__global__ __launch_bounds__(256) void gemm_bt2(
    const ushort_t* __restrict__ A,   // [N,K] bf16
    const ushort_t* __restrict__ Wt,  // [Nout,K] bf16
    ushort_t* __restrict__ Out,       // [N,Nld] bf16
    int Nld)
{
    __shared__ ushort_t As[128 * 128];
    __shared__ ushort_t Bs[64 * 128];
    const int tid = threadIdx.x;
    int mt, nc;
    swz<NC>(blockIdx.x, mt, nc);
    const int m0 = mt * 128;
    const int n0 = nc * 64;
    const int wv = tid >> 6, lane = tid & 63;
    const int lr = lane & 15, lq = lane >> 4;
    const int tr = tid >> 4, tc = tid & 15;
    const int sc = ((tr + tc) & 15) << 3;
    const int wbase = tid & 192;

    f32x4 acc[2][4];
    #pragma unroll
    for (int rt = 0; rt < 2; ++rt)
        #pragma unroll
        for (int ct = 0; ct < 4; ++ct)
            #pragma unroll
            for (int e = 0; e < 4; ++e) acc[rt][ct][e] = 0.0f;

    for (int t = 0; t < K / 128; ++t) {
        const int k0 = t * 128;
        const ushort_t* ga = A + (size_t)(m0 + tr) * K + k0 + sc;
        #pragma unroll
        for (int i = 0; i < 8; ++i)
            gll16(ga + (size_t)i * 16 * K, &As[(i * 256 + wbase) * 8]);
        const ushort_t* gb = Wt + (size_t)(n0 + tr) * K + k0 + sc;
        #pragma unroll
        for (int i = 0; i < 4; ++i)
            gll16(gb + (size_t)i * 16 * K, &Bs[(i * 256 + wbase) * 8]);
        __syncthreads();
        #pragma unroll
        for (int kk = 0; kk < 128; kk += 32) {
            const int g8 = (kk >> 3) + lq;
            bf16x8 a0 = ldsw(As, wv * 32 + lr, g8);
            bf16x8 a1 = ldsw(As, wv * 32 + 16 + lr, g8);
            #pragma unroll
            for (int ct = 0; ct < 4; ++ct) {
                bf16x8 b = ldsw(Bs, ct * 16 + lr, g8);
                acc[0][ct] = __builtin_amdgcn_mfma_f32_16x16x32_bf16(a0, b, acc[0][ct], 0, 0, 0);
                acc[1][ct] = __builtin_amdgcn_mfma_f32_16x16x32_bf16(a1, b, acc[1][ct], 0, 0, 0);
            }
        }
        __syncthreads();
    }

    #pragma unroll
    for (int ct = 0; ct < 4; ++ct) {
        const int col = n0 + ct * 16 + lr;
        #pragma unroll
        for (int rt = 0; rt < 2; ++rt) {
            #pragma unroll
            for (int r = 0; r < 4; ++r) {
                const int row = m0 + wv * 32 + rt * 16 + lq * 4 + r;
                Out[(size_t)row * Nld + col] = f2bf(acc[rt][ct][r]);
            }
        }
    }
}

// ---------------------------------------------------------------------------
// GCN chain aggregation, 8 cols/thread: g[i]=di*(dm*x[i-1]+di*x[i]+dp*x[i+1])+b
// ---------------------------------------------------------------------------
__global__ __launch_bounds__(256) void stencil8(
    const ushort_t* __restrict__ xw, const float* __restrict__ bias,
    ushort_t* __restrict__ g)
{
    const float S2 = 0.70710678118654752f, S3 = 0.57735026918962576f;
    int idx = blockIdx.x * 256 + threadIdx.x;   // N*16 chunks
    int i = idx >> 4, c8 = (idx & 15) << 3;
    float di = (i == 0 || i == N_NODES - 1) ? S2 : S3;
    bool hm = i > 0, hp = i < N_NODES - 1;
    float dm = hm ? ((i - 1 == 0) ? S2 : S3) : 0.0f;
    float dp = hp ? ((i + 1 == N_NODES - 1) ? S2 : S3) : 0.0f;
    us8 v0 = *(const us8*)(xw + (size_t)i * 128 + c8);
    us8 vm = *(const us8*)(xw + (size_t)(hm ? i - 1 : i) * 128 + c8);
    us8 vp = *(const us8*)(xw + (size_t)(hp ? i + 1 : i) * 128 + c8);
    us8 o;
    #pragma unroll
    for (int e = 0; e < 8; ++e) {
        float s = di * bf2f(v0[e]) + dm * bf2f(vm[e]) + dp * bf2f(vp[e]);
        o[e] = f2bf(di * s + bias[c8 + e]);
    }
    *(us8*)&g[(size_t)i * 128 + c8] = o;
}

// ---------------------------------------------------------------------------
// Final: GCN2 aggregation (C=64) + bias + FC [64->10] + bias. fp32 out.
// ---------------------------------------------------------------------------
__global__ __launch_bounds__(256) void final_fc(
    const ushort_t* __restrict__ xw2,   // [N,64] bf16
    const float* __restrict__ b_g2,     // [64]
    const float* __restrict__ w_fc,     // [64,10]
    const float* __restrict__ b_fc,     // [10]
    float* __restrict__ out)            // [N,10] fp32
{
    __shared__ float wfc_s[640];
    __shared__ float bg2_s[64];
    __shared__ float bfc_s[10];
    const int tid = threadIdx.x;
    for (int t = tid; t < 640; t += 256) wfc_s[t] = w_fc[t];
    if (tid < 64) bg2_s[tid] = b_g2[tid];
    if (tid < 10) bfc_s[tid] = b_fc[tid];
    __syncthreads();

    const float S2 = 0.70710678118654752f, S3 = 0.57735026918962576f;
    const int i = blockIdx.x * 256 + tid;
    float di = (i == 0 || i == N_NODES - 1) ? S2 : S3;
    bool hm = i > 0, hp = i < N_NODES - 1;
    float dm = hm ? ((i - 1 == 0) ? S2 : S3) : 0.0f;
    float dp = hp ? ((i + 1 == N_NODES - 1) ? S2 : S3) : 0.0f;
    const ushort_t* r0 = xw2 + (size_t)i * 64;
    const ushort_t* rm = xw2 + (size_t)(hm ? i - 1 : i) * 64;
    const ushort_t* rp = xw2 + (size_t)(hp ? i + 1 : i) * 64;

    float o[10];
    #pragma unroll
    for (int k = 0; k < 10; ++k) o[k] = bfc_s[k];
    #pragma unroll
    for (int c8 = 0; c8 < 8; ++c8) {
        us8 v0 = *(const us8*)&r0[c8 * 8];
        us8 vm = *(const us8*)&rm[c8 * 8];
        us8 vp = *(const us8*)&rp[c8 * 8];
        #pragma unroll
        for (int e = 0; e < 8; ++e) {
            int c = c8 * 8 + e;
            float s = di * bf2f(v0[e]) + dm * bf2f(vm[e]) + dp * bf2f(vp[e]);
            float g2 = di * s + bg2_s[c];
            #pragma unroll
            for (int k = 0; k < 10; ++k) o[k] += g2 * wfc_s[c * 10 + k];
        }
    }
    #pragma unroll
    for (int k = 0; k < 10; ++k) out[(size_t)i * 10 + k] = o[k];
}

extern "C" void kernel_launch(void* const* d_in, const int* in_sizes, int n_in,
                              void* d_out, int out_size, void* d_ws, size_t ws_size,
                              hipStream_t stream) {
    const float* x     = (const float*)d_in[0];
    const float* w_f1  = (const float*)d_in[1];
    const float* bi_f1 = (const float*)d_in[2];
    const float* bh_f1 = (const float*)d_in[3];
    const float* w_b1  = (const float*)d_in[4];
    const float* bi_b1 = (const float*)d_in[5];
    const float* bh_b1 = (const float*)d_in[6];
    const float* w_f2  = (const float*)d_in[7];
    const float* bi_f2 = (const float*)d_in[8];
    const float* bh_f2 = (const float*)d_in[9];
    const float* w_b2  = (const float*)d_in[10];
    const float* bi_b2 = (const float*)d_in[11];
    const float* bh_b2 = (const float*)d_in[12];
    const float* w_g1  = (const float*)d_in[13];
    const float* b_g1  = (const float*)d_in[14];
    const float* w_g2  = (const float*)d_in[15];
    const float* b_g2  = (const float*)d_in[16];
    const float* w_fc  = (const float*)d_in[17];
    const float* b_fc  = (const float*)d_in[18];

    char* ws = (char*)d_ws;
    ushort_t* h1   = (ushort_t*)(ws);                    // [N,256], dies after layer2
    ushort_t* xb   = (ushort_t*)(ws + 67108864);         // [N,128] bf16 x, dies after layer1
    ushort_t* h2   = (ushort_t*)(ws + 67108864);         // [N,256], overwrites dead xb
    ushort_t* xw1  = (ushort_t*)(ws);                    // [N,128], reuse dead h1
    ushort_t* g1   = (ushort_t*)(ws + 33554432);         // [N,128]
    ushort_t* xw2  = (ushort_t*)(ws + 67108864);         // [N,64], reuse dead h2
    ushort_t* PWF1 = (ushort_t*)(ws + 134217728);        // [384,128]
    ushort_t* PWB1 = PWF1 + 49152;
    ushort_t* PWF2 = PWB1 + 49152;                       // [384,256]
    ushort_t* PWB2 = PWF2 + 98304;
    ushort_t* WT1  = PWB2 + 98304;                       // [128,256]
    ushort_t* WT2  = WT1 + 32768;                        // [64,128]

    prep_weights<<<1312, 256, 0, stream>>>(w_f1, w_b1, w_f2, w_b2, w_g1, w_g2,
                                           PWF1, PWB1, PWF2, PWB2, WT1, WT2);
    xconv<<<N_NODES * 16 / 256, 256, 0, stream>>>(x, xb);

    gru_gemm2<128><<<N_NODES / 128 * 8, 256, 0, stream>>>(
        xb, PWF1, PWB1, bi_f1, bh_f1, bi_b1, bh_b1, h1);
    gru_gemm2<256><<<N_NODES / 128 * 8, 256, 0, stream>>>(
        h1, PWF2, PWB2, bi_f2, bh_f2, bi_b2, bh_b2, h2);

    gemm_bt2<256, 2><<<N_NODES / 128 * 2, 256, 0, stream>>>(h2, WT1, xw1, 128);
    stencil8<<<N_NODES * 16 / 256, 256, 0, stream>>>(xw1, b_g1, g1);
    gemm_bt2<128, 1><<<N_NODES / 128, 256, 0, stream>>>(g1, WT2, xw2, 64);
    final_fc<<<N_NODES / 256, 256, 0, stream>>>(xw2, b_g2, w_fc, b_fc, (float*)d_out);
}

// Round 7
// 303.693 us; speedup vs baseline: 1.9289x; 1.0500x over previous
//
#include <hip/hip_runtime.h>
#include <stdint.h>

#define N_NODES 131072
#define HDIM 128

typedef __bf16 bf16x8 __attribute__((ext_vector_type(8)));
typedef float f32x4 __attribute__((ext_vector_type(4)));
typedef unsigned short us8 __attribute__((ext_vector_type(8)));
typedef unsigned short ushort_t;

__device__ __forceinline__ float bf2f(ushort_t u) {
    union { float f; uint32_t i; } v; v.i = ((uint32_t)u) << 16; return v.f;
}
__device__ __forceinline__ ushort_t f2bf(float f) {
    union { float f; uint32_t i; } v; v.f = f;
    uint32_t i = v.i;
    return (ushort_t)((i + 0x7FFFu + ((i >> 16) & 1u)) >> 16);  // RNE
}

// async global->LDS 16B DMA: LDS dest = wave-uniform base + lane*16
__device__ __forceinline__ void gll16(const ushort_t* g, ushort_t* l) {
    __builtin_amdgcn_global_load_lds(
        (const __attribute__((address_space(1))) uint32_t*)g,
        (__attribute__((address_space(3))) uint32_t*)l, 16, 0, 0);
}

// BK=64 rot swizzle: LDS row r slot c holds global chunk (c+r)&7 (16B chunks)
__device__ __forceinline__ bf16x8 ldsw(const ushort_t* base, int R, int g) {
    return *(const bf16x8*)&base[R * 64 + (((g - R) & 7) << 3)];
}

// fast sigmoid / tanh via v_exp_f32 + v_rcp_f32 (bf16-accurate)
__device__ __forceinline__ float fsig(float x) {
    return __builtin_amdgcn_rcpf(1.0f + __expf(-x));
}
__device__ __forceinline__ float ftanh(float y) {
    float yc = fminf(fmaxf(y, -15.0f), 15.0f);
    float e = __expf(2.0f * yc);
    return (e - 1.0f) * __builtin_amdgcn_rcpf(e + 1.0f);
}

// XCD-temporal block swizzle: NC combos of one m-tile share (id mod 8) -> same
// XCD, and sit within an 8*NC-id window -> co-resident -> L2 A-tile reuse.
// [verified R6: FETCH 264->34 MB]
template<int NC>
__device__ __forceinline__ void swz(int b, int& m, int& c) {
    int mhi = b / (8 * NC);
    int rem = b - mhi * (8 * NC);
    c = rem >> 3;
    m = mhi * 8 + (rem & 7);
}

// ---------------------------------------------------------------------------
// prep: fp32->bf16 weight conversion (+ transpose for GCN weights)
// ---------------------------------------------------------------------------
__global__ __launch_bounds__(256) void prep_weights(
    const float* __restrict__ w_f1, const float* __restrict__ w_b1,
    const float* __restrict__ w_f2, const float* __restrict__ w_b2,
    const float* __restrict__ w_g1, const float* __restrict__ w_g2,
    ushort_t* __restrict__ PWF1, ushort_t* __restrict__ PWB1,
    ushort_t* __restrict__ PWF2, ushort_t* __restrict__ PWB2,
    ushort_t* __restrict__ WT1,  ushort_t* __restrict__ WT2)
{
    int idx = blockIdx.x * 256 + threadIdx.x;
    if (idx < 49152) {
        PWF1[idx] = f2bf(w_f1[idx]);
    } else if (idx < 98304) {
        int j = idx - 49152;  PWB1[j] = f2bf(w_b1[j]);
    } else if (idx < 196608) {
        int j = idx - 98304;  PWF2[j] = f2bf(w_f2[j]);
    } else if (idx < 294912) {
        int j = idx - 196608; PWB2[j] = f2bf(w_b2[j]);
    } else if (idx < 327680) {
        int j = idx - 294912; int k = j >> 7, o = j & 127;   // w_g1 [256,128]
        WT1[o * 256 + k] = f2bf(w_g1[j]);                    // WT1 [128,256]
    } else if (idx < 335872) {
        int j = idx - 327680; int k = j >> 6, o = j & 63;    // w_g2 [128,64]
        WT2[o * 128 + k] = f2bf(w_g2[j]);                    // WT2 [64,128]
    }
}

// x fp32 [N,128] -> bf16, 8 elems/thread
__global__ __launch_bounds__(256) void xconv(
    const float* __restrict__ x, ushort_t* __restrict__ xb)
{
    int idx = blockIdx.x * 256 + threadIdx.x;   // N*16 chunks
    const float* s = x + (size_t)idx * 8;
    float4 f0 = ((const float4*)s)[0];
    float4 f1 = ((const float4*)s)[1];
    us8 t;
    t[0] = f2bf(f0.x); t[1] = f2bf(f0.y); t[2] = f2bf(f0.z); t[3] = f2bf(f0.w);
    t[4] = f2bf(f1.x); t[5] = f2bf(f1.y); t[6] = f2bf(f1.z); t[7] = f2bf(f1.w);
    *(us8*)&xb[(size_t)idx * 8] = t;
}

// ---------------------------------------------------------------------------
// Fused GRU GEMM (both directions), BK=64, 28KB LDS -> 5 blocks/CU.
// 1D grid 8*N/128 with XCD-temporal swizzle.
// ---------------------------------------------------------------------------
template<int K>
__global__ __launch_bounds__(256, 5) void gru_gemm2(
    const ushort_t* __restrict__ A,      // [N,K] bf16
    const ushort_t* __restrict__ Wf,     // [384,K] bf16
    const ushort_t* __restrict__ Wb,     // [384,K] bf16
    const float* __restrict__ bi_f, const float* __restrict__ bh_f,
    const float* __restrict__ bi_b, const float* __restrict__ bh_b,
    ushort_t* __restrict__ Hout)         // [N,256] bf16
{
    __shared__ ushort_t As[128 * 64];    // 16 KB
    __shared__ ushort_t Bs[96 * 64];     // 12 KB
    const int tid = threadIdx.x;
    int mt, comb;
    swz<8>(blockIdx.x, mt, comb);
    const int m0 = mt * 128;
    const int dir = comb >> 2;
    const int j0 = (comb & 3) * 32;
    const ushort_t* W = dir ? Wb : Wf;
    const float* b_ih = dir ? bi_b : bi_f;
    const float* b_hh = dir ? bh_b : bh_f;
    const int coloff = dir << 7;

    const int wv = tid >> 6, lane = tid & 63;
    const int lr = lane & 15, lq = lane >> 4;
    const int tr = tid >> 3, tc = tid & 7;      // 32 rows x 8 chunks per pass
    const int sc = ((tr + tc) & 7) << 3;        // rotated source chunk (shorts)

    f32x4 acc[3][2][2];
    #pragma unroll
    for (int g = 0; g < 3; ++g)
        #pragma unroll
        for (int rt = 0; rt < 2; ++rt)
            #pragma unroll
            for (int ct = 0; ct < 2; ++ct)
                #pragma unroll
                for (int e = 0; e < 4; ++e) acc[g][rt][ct][e] = 0.0f;

    for (int t = 0; t < K / 64; ++t) {
        const int k0 = t * 64;
        // A tile 128x64: 4 passes of 32 rows
        const ushort_t* ga = A + (size_t)(m0 + tr) * K + k0 + sc;
        #pragma unroll
        for (int i = 0; i < 4; ++i)
            gll16(ga + (size_t)i * 32 * K, &As[(i * 256 + tid) * 8]);
        // B tile 96x64: pass i = gate strip i, rows j0..j0+31
        #pragma unroll
        for (int i = 0; i < 3; ++i) {
            int wr = (i << 7) + j0 + tr;
            gll16(W + (size_t)wr * K + k0 + sc, &Bs[(i * 256 + tid) * 8]);
        }
        __syncthreads();
        #pragma unroll
        for (int kk = 0; kk < 64; kk += 32) {
            const int g8 = (kk >> 3) + lq;
            bf16x8 a0 = ldsw(As, wv * 32 + lr, g8);
            bf16x8 a1 = ldsw(As, wv * 32 + 16 + lr, g8);
            #pragma unroll
            for (int g = 0; g < 3; ++g) {
                #pragma unroll
                for (int ct = 0; ct < 2; ++ct) {
                    bf16x8 b = ldsw(Bs, g * 32 + ct * 16 + lr, g8);
                    acc[g][0][ct] = __builtin_amdgcn_mfma_f32_16x16x32_bf16(a0, b, acc[g][0][ct], 0, 0, 0);
                    acc[g][1][ct] = __builtin_amdgcn_mfma_f32_16x16x32_bf16(a1, b, acc[g][1][ct], 0, 0, 0);
                }
            }
        }
        __syncthreads();
    }

    // epilogue: C/D layout col=lane&15, row=(lane>>4)*4+reg [m89/m91]
    #pragma unroll
    for (int ct = 0; ct < 2; ++ct) {
        const int j = j0 + ct * 16 + lr;
        const float br  = b_ih[j] + b_hh[j];
        const float bz  = b_ih[HDIM + j] + b_hh[HDIM + j];
        const float bn  = b_ih[2 * HDIM + j];
        const float bhn = b_hh[2 * HDIM + j];
        #pragma unroll
        for (int rt = 0; rt < 2; ++rt) {
            #pragma unroll
            for (int r = 0; r < 4; ++r) {
                const int row = m0 + wv * 32 + rt * 16 + lq * 4 + r;
                float rg = fsig(acc[0][rt][ct][r] + br);
                float zg = fsig(acc[1][rt][ct][r] + bz);
                float ng = ftanh(acc[2][rt][ct][r] + bn + rg * bhn);
                Hout[(size_t)row * 256 + coloff + j] = f2bf((1.0f - zg) * ng);
            }
        }
    }
}

// ---------------------------------------------------------------------------
// Plain GEMM Out = A @ Wt^T, BK=64, 24KB LDS. 1D grid NC*N/128, XCD swizzle.
// ---------------------------------------------------------------------------
template<int K, int NC>
__global__ __launch_bounds__(256, 5) void gemm_bt2(
    const ushort_t* __restrict__ A,   // [N,K] bf16
    const ushort_t* __restrict__ Wt,  // [Nout,K] bf16
    ushort_t* __restrict__ Out,       // [N,Nld] bf16
    int Nld)
{
    __shared__ ushort_t As[128 * 64];   // 16 KB
    __shared__ ushort_t Bs[64 * 64];    // 8 KB
    const int tid = threadIdx.x;
    int mt, nc;
    swz<NC>(blockIdx.x, mt, nc);
    const int m0 = mt * 128;
    const int n0 = nc * 64;
    const int wv = tid >> 6, lane = tid & 63;
    const int lr = lane & 15, lq = lane >> 4;
    const int tr = tid >> 3, tc = tid & 7;
    const int sc = ((tr + tc) & 7) << 3;

    f32x4 acc[2][4];
    #pragma unroll
    for (int rt = 0; rt < 2; ++rt)
        #pragma unroll
        for (int ct = 0; ct < 4; ++ct)
            #pragma unroll
            for (int e = 0; e < 4; ++e) acc[rt][ct][e] = 0.0f;

    for (int t = 0; t < K / 64; ++t) {
        const int k0 = t * 64;
        const ushort_t* ga = A + (size_t)(m0 + tr) * K + k0 + sc;
        #pragma unroll
        for (int i = 0; i < 4; ++i)
            gll16(ga + (size_t)i * 32 * K, &As[(i * 256 + tid) * 8]);
        const ushort_t* gb = Wt + (size_t)(n0 + tr) * K + k0 + sc;
        #pragma unroll
        for (int i = 0; i < 2; ++i)
            gll16(gb + (size_t)i * 32 * K, &Bs[(i * 256 + tid) * 8]);
        __syncthreads();
        #pragma unroll
        for (int kk = 0; kk < 64; kk += 32) {
            const int g8 = (kk >> 3) + lq;
            bf16x8 a0 = ldsw(As, wv * 32 + lr, g8);
            bf16x8 a1 = ldsw(As, wv * 32 + 16 + lr, g8);
            #pragma unroll
            for (int ct = 0; ct < 4; ++ct) {
                bf16x8 b = ldsw(Bs, ct * 16 + lr, g8);
                acc[0][ct] = __builtin_amdgcn_mfma_f32_16x16x32_bf16(a0, b, acc[0][ct], 0, 0, 0);
                acc[1][ct] = __builtin_amdgcn_mfma_f32_16x16x32_bf16(a1, b, acc[1][ct], 0, 0, 0);
            }
        }
        __syncthreads();
    }

    #pragma unroll
    for (int ct = 0; ct < 4; ++ct) {
        const int col = n0 + ct * 16 + lr;
        #pragma unroll
        for (int rt = 0; rt < 2; ++rt) {
            #pragma unroll
            for (int r = 0; r < 4; ++r) {
                const int row = m0 + wv * 32 + rt * 16 + lq * 4 + r;
                Out[(size_t)row * Nld + col] = f2bf(acc[rt][ct][r]);
            }
        }
    }
}

// ---------------------------------------------------------------------------
// GCN chain aggregation, 8 cols/thread: g[i]=di*(dm*x[i-1]+di*x[i]+dp*x[i+1])+b
// ---------------------------------------------------------------------------
__global__ __launch_bounds__(256) void stencil8(
    const ushort_t* __restrict__ xw, const float* __restrict__ bias,
    ushort_t* __restrict__ g)
{
    const float S2 = 0.70710678118654752f, S3 = 0.57735026918962576f;
    int idx = blockIdx.x * 256 + threadIdx.x;   // N*16 chunks
    int i = idx >> 4, c8 = (idx & 15) << 3;
    float di = (i == 0 || i == N_NODES - 1) ? S2 : S3;
    bool hm = i > 0, hp = i < N_NODES - 1;
    float dm = hm ? ((i - 1 == 0) ? S2 : S3) : 0.0f;
    float dp = hp ? ((i + 1 == N_NODES - 1) ? S2 : S3) : 0.0f;
    us8 v0 = *(const us8*)(xw + (size_t)i * 128 + c8);
    us8 vm = *(const us8*)(xw + (size_t)(hm ? i - 1 : i) * 128 + c8);
    us8 vp = *(const us8*)(xw + (size_t)(hp ? i + 1 : i) * 128 + c8);
    us8 o;
    #pragma unroll
    for (int e = 0; e < 8; ++e) {
        float s = di * bf2f(v0[e]) + dm * bf2f(vm[e]) + dp * bf2f(vp[e]);
        o[e] = f2bf(di * s + bias[c8 + e]);
    }
    *(us8*)&g[(size_t)i * 128 + c8] = o;
}

// ---------------------------------------------------------------------------
// Final: GCN2 aggregation (C=64) + bias + FC [64->10] + bias. fp32 out.
// ---------------------------------------------------------------------------
__global__ __launch_bounds__(256) void final_fc(
    const ushort_t* __restrict__ xw2,   // [N,64] bf16
    const float* __restrict__ b_g2,     // [64]
    const float* __restrict__ w_fc,     // [64,10]
    const float* __restrict__ b_fc,     // [10]
    float* __restrict__ out)            // [N,10] fp32
{
    __shared__ float wfc_s[640];
    __shared__ float bg2_s[64];
    __shared__ float bfc_s[10];
    const int tid = threadIdx.x;
    for (int t = tid; t < 640; t += 256) wfc_s[t] = w_fc[t];
    if (tid < 64) bg2_s[tid] = b_g2[tid];
    if (tid < 10) bfc_s[tid] = b_fc[tid];
    __syncthreads();

    const float S2 = 0.70710678118654752f, S3 = 0.57735026918962576f;
    const int i = blockIdx.x * 256 + tid;
    float di = (i == 0 || i == N_NODES - 1) ? S2 : S3;
    bool hm = i > 0, hp = i < N_NODES - 1;
    float dm = hm ? ((i - 1 == 0) ? S2 : S3) : 0.0f;
    float dp = hp ? ((i + 1 == N_NODES - 1) ? S2 : S3) : 0.0f;
    const ushort_t* r0 = xw2 + (size_t)i * 64;
    const ushort_t* rm = xw2 + (size_t)(hm ? i - 1 : i) * 64;
    const ushort_t* rp = xw2 + (size_t)(hp ? i + 1 : i) * 64;

    float o[10];
    #pragma unroll
    for (int k = 0; k < 10; ++k) o[k] = bfc_s[k];
    #pragma unroll
    for (int c8 = 0; c8 < 8; ++c8) {
        us8 v0 = *(const us8*)&r0[c8 * 8];
        us8 vm = *(const us8*)&rm[c8 * 8];
        us8 vp = *(const us8*)&rp[c8 * 8];
        #pragma unroll
        for (int e = 0; e < 8; ++e) {
            int c = c8 * 8 + e;
            float s = di * bf2f(v0[e]) + dm * bf2f(vm[e]) + dp * bf2f(vp[e]);
            float g2 = di * s + bg2_s[c];
            #pragma unroll
            for (int k = 0; k < 10; ++k) o[k] += g2 * wfc_s[c * 10 + k];
        }
    }
    #pragma unroll
    for (int k = 0; k < 10; ++k) out[(size_t)i * 10 + k] = o[k];
}

extern "C" void kernel_launch(void* const* d_in, const int* in_sizes, int n_in,
                              void* d_out, int out_size, void* d_ws, size_t ws_size,
                              hipStream_t stream) {
    const float* x     = (const float*)d_in[0];
    const float* w_f1  = (const float*)d_in[1];
    const float* bi_f1 = (const float*)d_in[2];
    const float* bh_f1 = (const float*)d_in[3];
    const float* w_b1  = (const float*)d_in[4];
    const float* bi_b1 = (const float*)d_in[5];
    const float* bh_b1 = (const float*)d_in[6];
    const float* w_f2  = (const float*)d_in[7];
    const float* bi_f2 = (const float*)d_in[8];
    const float* bh_f2 = (const float*)d_in[9];
    const float* w_b2  = (const float*)d_in[10];
    const float* bi_b2 = (const float*)d_in[11];
    const float* bh_b2 = (const float*)d_in[12];
    const float* w_g1  = (const float*)d_in[13];
    const float* b_g1  = (const float*)d_in[14];
    const float* w_g2  = (const float*)d_in[15];
    const float* b_g2  = (const float*)d_in[16];
    const float* w_fc  = (const float*)d_in[17];
    const float* b_fc  = (const float*)d_in[18];

    char* ws = (char*)d_ws;
    ushort_t* h1   = (ushort_t*)(ws);                    // [N,256], dies after layer2
    ushort_t* xb   = (ushort_t*)(ws + 67108864);         // [N,128] bf16 x, dies after layer1
    ushort_t* h2   = (ushort_t*)(ws + 67108864);         // [N,256], overwrites dead xb
    ushort_t* xw1  = (ushort_t*)(ws);                    // [N,128], reuse dead h1
    ushort_t* g1   = (ushort_t*)(ws + 33554432);         // [N,128]
    ushort_t* xw2  = (ushort_t*)(ws + 67108864);         // [N,64], reuse dead h2
    ushort_t* PWF1 = (ushort_t*)(ws + 134217728);        // [384,128]
    ushort_t* PWB1 = PWF1 + 49152;
    ushort_t* PWF2 = PWB1 + 49152;                       // [384,256]
    ushort_t* PWB2 = PWF2 + 98304;
    ushort_t* WT1  = PWB2 + 98304;                       // [128,256]
    ushort_t* WT2  = WT1 + 32768;                        // [64,128]

    prep_weights<<<1312, 256, 0, stream>>>(w_f1, w_b1, w_f2, w_b2, w_g1, w_g2,
                                           PWF1, PWB1, PWF2, PWB2, WT1, WT2);
    xconv<<<N_NODES * 16 / 256, 256, 0, stream>>>(x, xb);

    gru_gemm2<128><<<N_NODES / 128 * 8, 256, 0, stream>>>(
        xb, PWF1, PWB1, bi_f1, bh_f1, bi_b1, bh_b1, h1);
    gru_gemm2<256><<<N_NODES / 128 * 8, 256, 0, stream>>>(
        h1, PWF2, PWB2, bi_f2, bh_f2, bi_b2, bh_b2, h2);

    gemm_bt2<256, 2><<<N_NODES / 128 * 2, 256, 0, stream>>>(h2, WT1, xw1, 128);
    stencil8<<<N_NODES * 16 / 256, 256, 0, stream>>>(xw1, b_g1, g1);
    gemm_bt2<128, 1><<<N_NODES / 128, 256, 0, stream>>>(g1, WT2, xw2, 64);
    final_fc<<<N_NODES / 256, 256, 0, stream>>>(xw2, b_g2, w_fc, b_fc, (float*)d_out);
}